// Round 5
// baseline (3480.218 us; speedup 1.0000x reference)
//
#include <hip/hip_runtime.h>
#include <hip/hip_bf16.h>

typedef __bf16 bf16x8 __attribute__((ext_vector_type(8)));
typedef float f32x4 __attribute__((ext_vector_type(4)));
typedef unsigned int u32;
typedef unsigned long long u64;

#define T_ 512
#define E_ 256
#define U_ 512

// ---------------- workspace layout (bytes) ----------------
// xs_g : bf16 [T][64][256] (granule-swizzled rows)                 16 MiB
// w2   : bf16 [2 dir][16 us][8 wv][24 j][64 lane][8] frag-ordered   6 MiB
// hpub : u32  [2 dir][2 par][4 q][16 us][16 b][32 u]  (h|epoch)   512 KiB
// hfin : f32  [2][64][512] (plain)                                256 KiB
static const size_t WS_XS = 0;
static const size_t WS_W2 = (size_t)16 << 20;
static const size_t WS_HP = WS_W2 + 6291456;
static const size_t WS_HF = WS_HP + 524288;

__device__ __forceinline__ float fsigm(float x) { return 1.f / (1.f + __expf(-x)); }
__device__ __forceinline__ float ftanh(float x) {
  float e = __expf(2.f * fabsf(x));
  float r = 1.f - 2.f / (e + 1.f);
  return copysignf(r, x);
}

// Embedding gather + bf16 convert + granule swizzle.
__global__ void embed_swz_kernel(const int* __restrict__ sent,
                                 const float* __restrict__ emb,
                                 __bf16* __restrict__ xs_g) {
  int id = blockIdx.x * 256 + threadIdx.x;
  int gx = id & 31;          // granule within row (32 x 8 bf16 = 256)
  int b  = (id >> 5) & 63;
  int t  = id >> 11;
  int idx = sent[b * T_ + t];            // sentence is [B][T]
  const float* src = emb + (size_t)idx * E_ + gx * 8;
  bf16x8 v;
#pragma unroll
  for (int j = 0; j < 8; ++j) v[j] = (__bf16)src[j];
  int gs = gx ^ (b & 7);                 // XOR swizzle keyed by batch row
  *(bf16x8*)(xs_g + (size_t)(t * 64 + b) * E_ + gs * 8) = v;
}

// Weight prep (fragment-ordered for direct coalesced global->reg in lstm_main)
// + zero-init of the self-validating h publication buffer.
__global__ void __launch_bounds__(256)
wprep_kernel(const float* __restrict__ Wx_f, const float* __restrict__ Wh_f,
             const float* __restrict__ Wx_b, const float* __restrict__ Wh_b,
             __bf16* __restrict__ w2, u32* __restrict__ hpub) {
  int bid = blockIdx.x;              // ((d*16+us)*8+wv)*6 + jg
  int tid = threadIdx.x;
  {
    int zid = bid * 256 + tid;
    if (zid < 131072) hpub[zid] = 0u;    // clear stale epochs (every call)
  }
  int jg = bid % 6;
  int wv = (bid / 6) & 7;
  int us = (bid / 48) & 15;
  int d  = bid / 768;
  int j    = jg * 4 + (tid >> 6);
  int lane = tid & 63;
  int c    = wv * 16 + (lane & 15);   // slice row 0..127
  int ul   = c >> 2, gate = c & 3;
  int n    = gate * 512 + us * 32 + ul;
  int k0   = j * 32 + (lane >> 4) * 8;
  const float* Wx = d ? Wx_b : Wx_f;
  const float* Wh = d ? Wh_b : Wh_f;
  bf16x8 v;
#pragma unroll
  for (int e = 0; e < 8; ++e) {
    int k = k0 + e;
    float f = (k < 256) ? Wx[(size_t)k * 2048 + n] : Wh[(size_t)(k - 256) * 2048 + n];
    v[e] = (__bf16)f;
  }
  size_t og = ((size_t)((d * 16 + us) * 8 + wv) * 24 + j) * 64 + lane;
  *(bf16x8*)(w2 + og * 8) = v;
}

// Persistent bidirectional LSTM. 128 WGs x 512 thr.
// WG = (dir, us 0..15, q 0..3): units 32us..+31, batches 16q..+15.
// h exchange: each thread publishes its (unit,batch) h as u32 (bf16<<16|epoch),
// fire-and-forget; consumers speculatively load + validate embedded epochs.
__global__ void __launch_bounds__(512)
lstm_main(const __bf16* __restrict__ xs_g, const __bf16* __restrict__ w2,
          u32* __restrict__ hpub, float* __restrict__ hfin,
          const float* __restrict__ b_f, const float* __restrict__ b_b) {
  __shared__ __align__(16) __bf16 xbuf[2][16 * 256];   // 2 x 8 KiB
  __shared__ __align__(16) __bf16 hbuf[16 * 512];      // 16 KiB

  const int wg   = blockIdx.x;
  const int dir  = wg >> 6;
  const int sl   = wg & 63;
  const int us   = sl >> 2;
  const int q    = sl & 3;
  const int tid  = threadIdx.x;
  const int wv   = tid >> 6;
  const int lane = tid & 63;
  const int bq_l = lane & 15;          // local batch / D col
  const int kq   = lane >> 4;          // k-quarter
  const int bsw  = bq_l & 7;           // swizzle key
  const int ul_own = wv * 4 + kq;      // owned local unit (0..31)
  const int u_own  = us * 32 + ul_own;
  const int b_own  = q * 16 + bq_l;

  // ---- weight fragments: direct coalesced global->reg ----
  bf16x8 wfrag[24];
  {
    const bf16x8* wp = (const bf16x8*)w2 +
                       ((size_t)((dir * 16 + us) * 8 + wv) * 24) * 64 + lane;
#pragma unroll
    for (int j = 0; j < 24; ++j) wfrag[j] = wp[j * 64];
  }

  const float* bias = dir ? b_b : b_f;
  const float bi  = bias[u_own];
  const float bff = bias[512 + u_own];
  const float bg  = bias[1024 + u_own];
  const float bo  = bias[1536 + u_own];
  float c_st = 0.f;

  // ---- producer publish address (word per (b,ul)); parity adds 32768 ----
  u32* const pb0 = hpub + ((size_t)((dir * 8 + q) * 16 + us) * 512) +
                   bq_l * 32 + ul_own;

  // ---- consumer constants: wave wv half-waves cover producers 2wv,2wv+1 ----
  const int us_p  = 2 * wv + (lane >> 5);
  const int lane5 = lane & 31;
  const int b_l   = lane5 >> 1;
  const int uh    = (lane5 & 1) * 16;
  const u32* const cb0 = hpub + ((size_t)((dir * 8 + q) * 16 + us_p) * 512) +
                         b_l * 32 + uh;
  const int ga  = 4 * us_p + (uh >> 3);
  const int csw = b_l & 7;
  __bf16* const cdst0 = hbuf + b_l * 512 + (((ga)     ^ csw) << 3);
  __bf16* const cdst1 = hbuf + b_l * 512 + (((ga + 1) ^ csw) << 3);

  // ---- stage x_0 (8 KiB: 512 granules, 1 per thread) ----
  {
    int t0 = dir ? (T_ - 1) : 0;
    const uint4* xsrc = (const uint4*)(xs_g + ((size_t)t0 * 64 + q * 16) * 256);
    ((uint4*)xbuf[0])[tid] = xsrc[tid];
  }
  __syncthreads();

  for (int t = 0;; ++t) {
    // ---- [P] speculative h loads (fly under the x-MFMAs) ----
    u32 w[16];
    const u32* csrc = cb0 + (t & 1) * 32768;
    if (t > 0) {
#pragma unroll
      for (int j = 0; j < 16; ++j)
        w[j] = __hip_atomic_load(csrc + j, __ATOMIC_RELAXED, __HIP_MEMORY_SCOPE_AGENT);
    }

    // ---- [A] x-part MFMAs ----
    f32x4 acc0 = {0.f, 0.f, 0.f, 0.f};
    f32x4 acc1 = {0.f, 0.f, 0.f, 0.f};
    const __bf16* xb = xbuf[t & 1];
#pragma unroll
    for (int j = 0; j < 8; ++j) {
      int g = j * 4 + kq;
      bf16x8 a = *(const bf16x8*)(xb + bq_l * 256 + ((g ^ bsw) << 3));
      if (j & 1) acc1 = __builtin_amdgcn_mfma_f32_16x16x32_bf16(wfrag[j], a, acc1, 0, 0, 0);
      else       acc0 = __builtin_amdgcn_mfma_f32_16x16x32_bf16(wfrag[j], a, acc0, 0, 0, 0);
    }

    if (t > 0) {
      // ---- [B] validate embedded epochs; retry until fresh ----
      const u32 ep = (u32)t;
      for (;;) {
        u32 bad = 0;
#pragma unroll
        for (int j = 0; j < 16; ++j) bad |= (w[j] ^ ep) & 0xFFFFu;
        if (!__any((int)bad)) break;
        __builtin_amdgcn_s_sleep(1);
#pragma unroll
        for (int j = 0; j < 16; ++j)
          w[j] = __hip_atomic_load(csrc + j, __ATOMIC_RELAXED, __HIP_MEMORY_SCOPE_AGENT);
      }
      // ---- [C] pack hi16 -> bf16 granules -> LDS ----
      uint4 g0, g1;
      g0.x = (w[0] >> 16)  | (w[1] & 0xFFFF0000u);
      g0.y = (w[2] >> 16)  | (w[3] & 0xFFFF0000u);
      g0.z = (w[4] >> 16)  | (w[5] & 0xFFFF0000u);
      g0.w = (w[6] >> 16)  | (w[7] & 0xFFFF0000u);
      g1.x = (w[8] >> 16)  | (w[9] & 0xFFFF0000u);
      g1.y = (w[10] >> 16) | (w[11] & 0xFFFF0000u);
      g1.z = (w[12] >> 16) | (w[13] & 0xFFFF0000u);
      g1.w = (w[14] >> 16) | (w[15] & 0xFFFF0000u);
      *(uint4*)cdst0 = g0;
      *(uint4*)cdst1 = g1;
      __syncthreads();
      // ---- [D] h-part MFMAs ----
#pragma unroll
      for (int j = 0; j < 16; ++j) {
        int g = j * 4 + kq;
        bf16x8 a = *(const bf16x8*)(hbuf + bq_l * 512 + ((g ^ bsw) << 3));
        if (j & 1) acc1 = __builtin_amdgcn_mfma_f32_16x16x32_bf16(wfrag[8 + j], a, acc1, 0, 0, 0);
        else       acc0 = __builtin_amdgcn_mfma_f32_16x16x32_bf16(wfrag[8 + j], a, acc0, 0, 0, 0);
      }
    }

    // ---- gates in registers ----
    const float zi = acc0[0] + acc1[0] + bi;
    const float zf = acc0[1] + acc1[1] + bff;
    const float zg = acc0[2] + acc1[2] + bg;
    const float zo = acc0[3] + acc1[3] + bo;
    c_st = fsigm(zf) * c_st + fsigm(zi) * ftanh(zg);
    const float hv = fsigm(zo) * ftanh(c_st);

    if (t == T_ - 1) {
      hfin[(size_t)dir * 32768 + b_own * 512 + u_own] = hv;
      break;
    }

    // ---- [E] publish own h word (fire-and-forget, self-validating) ----
    {
      union { __bf16 h; unsigned short s; } cv;
      cv.h = (__bf16)hv;
      u32 word = ((u32)cv.s << 16) | (u32)(t + 1);
      __hip_atomic_store(pb0 + ((t + 1) & 1) * 32768, word, __ATOMIC_RELAXED,
                         __HIP_MEMORY_SCOPE_AGENT);
    }
    // ---- prefetch x_{t+1} (all 512 threads, 1 granule each) ----
    {
      const int teff = dir ? (T_ - 2 - t) : (t + 1);
      const uint4* xsrc = (const uint4*)(xs_g + ((size_t)teff * 64 + q * 16) * 256);
      ((uint4*)xbuf[(t + 1) & 1])[tid] = xsrc[tid];
    }
    __syncthreads();
  }
}

// Final head: out = sigmoid((hcat @ W1 + b1) @ W2 + b2), all f32. One block.
__global__ void __launch_bounds__(1024)
dense_kernel(const float* __restrict__ hfin, const float* __restrict__ W1,
             const float* __restrict__ b1, const float* __restrict__ W2,
             const float* __restrict__ b2, float* __restrict__ out) {
  __shared__ float hid[64][64];
  const int t = threadIdx.x;
  const int b = t >> 4;
  const int jg = t & 15;           // 4 output cols each
  float a0 = b1[jg * 4 + 0], a1 = b1[jg * 4 + 1], a2 = b1[jg * 4 + 2], a3 = b1[jg * 4 + 3];
#pragma unroll 8
  for (int k = 0; k < 1024; ++k) {
    const float hv = hfin[(size_t)(k >> 9) * 32768 + b * 512 + (k & 511)];
    const float4 w = *(const float4*)(W1 + (size_t)k * 64 + jg * 4);
    a0 += hv * w.x; a1 += hv * w.y; a2 += hv * w.z; a3 += hv * w.w;
  }
  hid[b][jg * 4 + 0] = a0; hid[b][jg * 4 + 1] = a1;
  hid[b][jg * 4 + 2] = a2; hid[b][jg * 4 + 3] = a3;
  __syncthreads();
  if (t < 64) {
    float l = b2[0];
#pragma unroll 8
    for (int j = 0; j < 64; ++j) l += hid[t][j] * W2[j];
    out[t] = 1.f / (1.f + __expf(-l));
  }
}

extern "C" void kernel_launch(void* const* d_in, const int* in_sizes, int n_in,
                              void* d_out, int out_size, void* d_ws, size_t ws_size,
                              hipStream_t stream) {
  const int*   sent = (const int*)d_in[0];
  const float* emb  = (const float*)d_in[1];
  const float* Wx_f = (const float*)d_in[2];
  const float* Wh_f = (const float*)d_in[3];
  const float* b_f  = (const float*)d_in[4];
  const float* Wx_b = (const float*)d_in[5];
  const float* Wh_b = (const float*)d_in[6];
  const float* b_b  = (const float*)d_in[7];
  const float* W1   = (const float*)d_in[8];
  const float* b1   = (const float*)d_in[9];
  const float* W2   = (const float*)d_in[10];
  const float* b2   = (const float*)d_in[11];
  float* out = (float*)d_out;

  char* ws = (char*)d_ws;
  __bf16* xs_g = (__bf16*)(ws + WS_XS);
  __bf16* w2   = (__bf16*)(ws + WS_W2);
  u32*    hpub = (u32*)(ws + WS_HP);
  float*  hfin = (float*)(ws + WS_HF);

  hipLaunchKernelGGL(embed_swz_kernel, dim3(4096), dim3(256), 0, stream, sent, emb, xs_g);
  hipLaunchKernelGGL(wprep_kernel, dim3(1536), dim3(256), 0, stream,
                     Wx_f, Wh_f, Wx_b, Wh_b, w2, hpub);

  void* args[] = {(void*)&xs_g, (void*)&w2, (void*)&hpub, (void*)&hfin,
                  (void*)&b_f, (void*)&b_b};
  hipLaunchCooperativeKernel((void*)lstm_main, dim3(128), dim3(512), args, 0, stream);

  hipLaunchKernelGGL(dense_kernel, dim3(1), dim3(1024), 0, stream,
                     hfin, W1, b1, W2, b2, out);
}

// Round 6
// 1381.440 us; speedup vs baseline: 2.5193x; 2.5193x over previous
//
#include <hip/hip_runtime.h>
#include <hip/hip_bf16.h>

typedef __bf16 bf16x8 __attribute__((ext_vector_type(8)));
typedef float f32x4 __attribute__((ext_vector_type(4)));
typedef unsigned int u32;
typedef unsigned long long u64;

#define T_ 512
#define E_ 256
#define U_ 512

// ---------------- workspace layout (bytes) ----------------
// xs_g : bf16 [T][64][256] (granule-swizzled rows)                 16 MiB
// w2   : bf16 [2 dir][16 us][8 wv][24 j][64 lane][8] frag-ordered   6 MiB
// hpub : u32  [2 dir][2 par][4 q][16 us][16 b][32 u] (h<<16|epoch) 512 KiB
// hfin : f32  [2][64][512] (plain)                                256 KiB
static const size_t WS_XS = 0;
static const size_t WS_W2 = (size_t)16 << 20;
static const size_t WS_HP = WS_W2 + 6291456;
static const size_t WS_HF = WS_HP + 524288;

__device__ __forceinline__ float fsigm(float x) { return 1.f / (1.f + __expf(-x)); }
__device__ __forceinline__ float ftanh(float x) {
  float e = __expf(2.f * fabsf(x));
  float r = 1.f - 2.f / (e + 1.f);
  return copysignf(r, x);
}

// Embedding gather + bf16 convert + granule swizzle.
__global__ void embed_swz_kernel(const int* __restrict__ sent,
                                 const float* __restrict__ emb,
                                 __bf16* __restrict__ xs_g) {
  int id = blockIdx.x * 256 + threadIdx.x;
  int gx = id & 31;          // granule within row (32 x 8 bf16 = 256)
  int b  = (id >> 5) & 63;
  int t  = id >> 11;
  int idx = sent[b * T_ + t];            // sentence is [B][T]
  const float* src = emb + (size_t)idx * E_ + gx * 8;
  bf16x8 v;
#pragma unroll
  for (int j = 0; j < 8; ++j) v[j] = (__bf16)src[j];
  int gs = gx ^ (b & 7);                 // XOR swizzle keyed by batch row
  *(bf16x8*)(xs_g + (size_t)(t * 64 + b) * E_ + gs * 8) = v;
}

// Weight prep (fragment-ordered for direct coalesced global->reg in lstm_main)
// + zero-init of the self-validating h publication buffer (epochs cleared).
__global__ void __launch_bounds__(256)
wprep_kernel(const float* __restrict__ Wx_f, const float* __restrict__ Wh_f,
             const float* __restrict__ Wx_b, const float* __restrict__ Wh_b,
             __bf16* __restrict__ w2, u32* __restrict__ hpub) {
  int bid = blockIdx.x;              // ((d*16+us)*8+wv)*6 + jg
  int tid = threadIdx.x;
  {
    int zid = bid * 256 + tid;
    if (zid < 131072) hpub[zid] = 0u;    // clear stale epochs (every call)
  }
  int jg = bid % 6;
  int wv = (bid / 6) & 7;
  int us = (bid / 48) & 15;
  int d  = bid / 768;
  int j    = jg * 4 + (tid >> 6);
  int lane = tid & 63;
  int c    = wv * 16 + (lane & 15);   // slice row 0..127
  int ul   = c >> 2, gate = c & 3;
  int n    = gate * 512 + us * 32 + ul;
  int k0   = j * 32 + (lane >> 4) * 8;
  const float* Wx = d ? Wx_b : Wx_f;
  const float* Wh = d ? Wh_b : Wh_f;
  bf16x8 v;
#pragma unroll
  for (int e = 0; e < 8; ++e) {
    int k = k0 + e;
    float f = (k < 256) ? Wx[(size_t)k * 2048 + n] : Wh[(size_t)(k - 256) * 2048 + n];
    v[e] = (__bf16)f;
  }
  size_t og = ((size_t)((d * 16 + us) * 8 + wv) * 24 + j) * 64 + lane;
  *(bf16x8*)(w2 + og * 8) = v;
}

// Persistent bidirectional LSTM. 128 WGs x 512 thr.
// WG = (dir, us 0..15, q 0..3): units 32us..+31, batches 16q..+15.
// h exchange: slice = 512 u32 words (w = b*32+u), each (bf16 h)<<16 | epoch.
// Producer wave0 publishes its slice with 4 coalesced u64 atomics/lane
// (fire-and-forget, no vmcnt, no flag). Consumers speculatively load 8
// coalesced u64/thread, validate embedded epochs, retry on miss.
__global__ void __launch_bounds__(512)
lstm_main(const __bf16* __restrict__ xs_g, const __bf16* __restrict__ w2,
          u32* __restrict__ hpub, float* __restrict__ hfin,
          const float* __restrict__ b_f, const float* __restrict__ b_b) {
  __shared__ __align__(16) __bf16 xbuf[2][16 * 256];   // 2 x 8 KiB
  __shared__ __align__(16) __bf16 hbuf[16 * 512];      // 16 KiB
  __shared__ __align__(16) __bf16 h_stage[16 * 40];    // padded stride 40

  const int wg   = blockIdx.x;
  const int dir  = wg >> 6;
  const int sl   = wg & 63;
  const int us   = sl >> 2;
  const int q    = sl & 3;
  const int tid  = threadIdx.x;
  const int wv   = tid >> 6;
  const int lane = tid & 63;
  const int bq_l = lane & 15;          // local batch / D col
  const int kq   = lane >> 4;          // k-quarter
  const int bsw  = bq_l & 7;           // swizzle key
  const int ul_own = wv * 4 + kq;      // owned local unit (0..31)
  const int u_own  = us * 32 + ul_own;
  const int b_own  = q * 16 + bq_l;

  // ---- weight fragments: direct coalesced global->reg ----
  bf16x8 wfrag[24];
  {
    const bf16x8* wp = (const bf16x8*)w2 +
                       ((size_t)((dir * 16 + us) * 8 + wv) * 24) * 64 + lane;
#pragma unroll
    for (int j = 0; j < 24; ++j) wfrag[j] = wp[j * 64];
  }

  const float* bias = dir ? b_b : b_f;
  const float bi  = bias[u_own];
  const float bff = bias[512 + u_own];
  const float bg  = bias[1024 + u_own];
  const float bo  = bias[1536 + u_own];
  float c_st = 0.f;

  // ---- producer store bases (wave0 lane covers u64 idx lane*4..+3) ----
  u64* const ps0 = (u64*)(hpub + ((size_t)(dir * 2 + 0) * 64 + q * 16 + us) * 512) + lane * 4;
  u64* const ps1 = (u64*)(hpub + ((size_t)(dir * 2 + 1) * 64 + q * 16 + us) * 512) + lane * 4;

  // ---- consumer bases: half-wave covers producer us_p's 2KB slice ----
  const int us_p  = 2 * wv + (lane >> 5);
  const int lane5 = lane & 31;
  const u64* const cs0 = (const u64*)(hpub + ((size_t)(dir * 2 + 0) * 64 + q * 16 + us_p) * 512) + lane5;
  const u64* const cs1 = (const u64*)(hpub + ((size_t)(dir * 2 + 1) * 64 + q * 16 + us_p) * 512) + lane5;
  // per-j LDS dst byte offsets (static per thread)
  int cdst[8];
#pragma unroll
  for (int j = 0; j < 8; ++j) {
    int b  = 2 * j + (lane5 >> 4);
    int u  = (lane5 & 15) * 2;
    int gg = us_p * 4 + (u >> 3);
    cdst[j] = b * 1024 + ((gg ^ (b & 7)) << 4) + ((u & 7) << 1);
  }

  // ---- stage x_0 (8 KiB: 512 granules, 1 per thread) ----
  {
    int t0 = dir ? (T_ - 1) : 0;
    const uint4* xsrc = (const uint4*)(xs_g + ((size_t)t0 * 64 + q * 16) * 256);
    ((uint4*)xbuf[0])[tid] = xsrc[tid];
  }
  __syncthreads();

  for (int t = 0;; ++t) {
    // ---- [P] speculative coalesced h loads (fly under the x-MFMAs) ----
    u64 v[8];
    const u64* csrc = (t & 1) ? cs1 : cs0;
    if (t > 0) {
#pragma unroll
      for (int j = 0; j < 8; ++j)
        v[j] = __hip_atomic_load(csrc + j * 32, __ATOMIC_RELAXED, __HIP_MEMORY_SCOPE_AGENT);
    }

    // ---- [A] x-part MFMAs ----
    f32x4 acc0 = {0.f, 0.f, 0.f, 0.f};
    f32x4 acc1 = {0.f, 0.f, 0.f, 0.f};
    const __bf16* xb = xbuf[t & 1];
#pragma unroll
    for (int j = 0; j < 8; ++j) {
      int g = j * 4 + kq;
      bf16x8 a = *(const bf16x8*)(xb + bq_l * 256 + ((g ^ bsw) << 3));
      if (j & 1) acc1 = __builtin_amdgcn_mfma_f32_16x16x32_bf16(wfrag[j], a, acc1, 0, 0, 0);
      else       acc0 = __builtin_amdgcn_mfma_f32_16x16x32_bf16(wfrag[j], a, acc0, 0, 0, 0);
    }

    if (t > 0) {
      // ---- [B] validate embedded epochs; retry until fresh ----
      const u32 ep = (u32)t;
      for (;;) {
        u32 bad = 0;
#pragma unroll
        for (int j = 0; j < 8; ++j)
          bad |= ((u32)v[j] ^ ep) | ((u32)(v[j] >> 32) ^ ep);
        bad &= 0xFFFFu;
        if (!__any((int)bad)) break;
        __builtin_amdgcn_s_sleep(1);
#pragma unroll
        for (int j = 0; j < 8; ++j)
          v[j] = __hip_atomic_load(csrc + j * 32, __ATOMIC_RELAXED, __HIP_MEMORY_SCOPE_AGENT);
      }
      // ---- [C] pack hi16 pairs -> LDS (8 x ds_write_b32) ----
#pragma unroll
      for (int j = 0; j < 8; ++j) {
        u32 pk = ((u32)(v[j] >> 32) & 0xFFFF0000u) | ((u32)v[j] >> 16);
        *(u32*)((char*)hbuf + cdst[j]) = pk;
      }
      __syncthreads();
      // ---- [D] h-part MFMAs ----
#pragma unroll
      for (int j = 0; j < 16; ++j) {
        int g = j * 4 + kq;
        bf16x8 a = *(const bf16x8*)(hbuf + bq_l * 512 + ((g ^ bsw) << 3));
        if (j & 1) acc1 = __builtin_amdgcn_mfma_f32_16x16x32_bf16(wfrag[8 + j], a, acc1, 0, 0, 0);
        else       acc0 = __builtin_amdgcn_mfma_f32_16x16x32_bf16(wfrag[8 + j], a, acc0, 0, 0, 0);
      }
    }

    // ---- gates in registers ----
    const float zi = acc0[0] + acc1[0] + bi;
    const float zf = acc0[1] + acc1[1] + bff;
    const float zg = acc0[2] + acc1[2] + bg;
    const float zo = acc0[3] + acc1[3] + bo;
    c_st = fsigm(zf) * c_st + fsigm(zi) * ftanh(zg);
    const float hv = fsigm(zo) * ftanh(c_st);

    if (t == T_ - 1) {
      hfin[(size_t)dir * 32768 + b_own * 512 + u_own] = hv;
      break;
    }
    h_stage[bq_l * 40 + ul_own] = (__bf16)hv;
    __syncthreads();   // h_stage complete; hbuf/xbuf reads done

    if (wv == 0) {
      // ---- [E] publish slice: lane -> batch lane>>2, units (lane&3)*8..+7 ----
      const u32 ep = (u32)(t + 1);
      uint4 hq = *(const uint4*)(h_stage + (lane >> 2) * 40 + (lane & 3) * 8);
      u64* pd = ((t + 1) & 1) ? ps1 : ps0;
#pragma unroll
      for (int e = 0; e < 4; ++e) {
        u32 pe = ((const u32*)&hq)[e];
        u64 wrd = ((u64)((pe & 0xFFFF0000u) | ep) << 32) | (u64)((pe << 16) | ep);
        __hip_atomic_store(pd + e, wrd, __ATOMIC_RELAXED, __HIP_MEMORY_SCOPE_AGENT);
      }
    } else {
      // waves 1-7: prefetch x_{t+1} (8 KiB)
      const int teff = dir ? (T_ - 2 - t) : (t + 1);
      const uint4* xsrc = (const uint4*)(xs_g + ((size_t)teff * 64 + q * 16) * 256);
      uint4* xdst = (uint4*)xbuf[(t + 1) & 1];
      for (int g2 = tid - 64; g2 < 512; g2 += 448) xdst[g2] = xsrc[g2];
    }
    __syncthreads();
  }
}

// Final head: out = sigmoid((hcat @ W1 + b1) @ W2 + b2), all f32. One block.
__global__ void __launch_bounds__(1024)
dense_kernel(const float* __restrict__ hfin, const float* __restrict__ W1,
             const float* __restrict__ b1, const float* __restrict__ W2,
             const float* __restrict__ b2, float* __restrict__ out) {
  __shared__ float hid[64][64];
  const int t = threadIdx.x;
  const int b = t >> 4;
  const int jg = t & 15;           // 4 output cols each
  float a0 = b1[jg * 4 + 0], a1 = b1[jg * 4 + 1], a2 = b1[jg * 4 + 2], a3 = b1[jg * 4 + 3];
#pragma unroll 8
  for (int k = 0; k < 1024; ++k) {
    const float hv = hfin[(size_t)(k >> 9) * 32768 + b * 512 + (k & 511)];
    const float4 w = *(const float4*)(W1 + (size_t)k * 64 + jg * 4);
    a0 += hv * w.x; a1 += hv * w.y; a2 += hv * w.z; a3 += hv * w.w;
  }
  hid[b][jg * 4 + 0] = a0; hid[b][jg * 4 + 1] = a1;
  hid[b][jg * 4 + 2] = a2; hid[b][jg * 4 + 3] = a3;
  __syncthreads();
  if (t < 64) {
    float l = b2[0];
#pragma unroll 8
    for (int j = 0; j < 64; ++j) l += hid[t][j] * W2[j];
    out[t] = 1.f / (1.f + __expf(-l));
  }
}

extern "C" void kernel_launch(void* const* d_in, const int* in_sizes, int n_in,
                              void* d_out, int out_size, void* d_ws, size_t ws_size,
                              hipStream_t stream) {
  const int*   sent = (const int*)d_in[0];
  const float* emb  = (const float*)d_in[1];
  const float* Wx_f = (const float*)d_in[2];
  const float* Wh_f = (const float*)d_in[3];
  const float* b_f  = (const float*)d_in[4];
  const float* Wx_b = (const float*)d_in[5];
  const float* Wh_b = (const float*)d_in[6];
  const float* b_b  = (const float*)d_in[7];
  const float* W1   = (const float*)d_in[8];
  const float* b1   = (const float*)d_in[9];
  const float* W2   = (const float*)d_in[10];
  const float* b2   = (const float*)d_in[11];
  float* out = (float*)d_out;

  char* ws = (char*)d_ws;
  __bf16* xs_g = (__bf16*)(ws + WS_XS);
  __bf16* w2   = (__bf16*)(ws + WS_W2);
  u32*    hpub = (u32*)(ws + WS_HP);
  float*  hfin = (float*)(ws + WS_HF);

  hipLaunchKernelGGL(embed_swz_kernel, dim3(4096), dim3(256), 0, stream, sent, emb, xs_g);
  hipLaunchKernelGGL(wprep_kernel, dim3(1536), dim3(256), 0, stream,
                     Wx_f, Wh_f, Wx_b, Wh_b, w2, hpub);

  void* args[] = {(void*)&xs_g, (void*)&w2, (void*)&hpub, (void*)&hfin,
                  (void*)&b_f, (void*)&b_b};
  hipLaunchCooperativeKernel((void*)lstm_main, dim3(128), dim3(512), args, 0, stream);

  hipLaunchKernelGGL(dense_kernel, dim3(1), dim3(1024), 0, stream,
                     hfin, W1, b1, W2, b2, out);
}

// Round 7
// 1308.276 us; speedup vs baseline: 2.6602x; 1.0559x over previous
//
#include <hip/hip_runtime.h>
#include <hip/hip_bf16.h>

typedef __bf16 bf16x8 __attribute__((ext_vector_type(8)));
typedef float f32x4 __attribute__((ext_vector_type(4)));
typedef unsigned int u32;
typedef unsigned short u16;
typedef unsigned long long u64;

#define T_ 512
#define E_ 256
#define U_ 512

// ---------------- workspace layout (bytes) ----------------
// xs_g : bf16 [T][64][256] (granule-swizzled rows)                 16 MiB
// w2   : bf16 [2 dir][16 us][8 wv][24 j][64 lane][8] frag-ordered   6 MiB
// hpub : u32  [2 dir][2 par][4 q][16 us][32 u][16 b] (h<<16|epoch) 512 KiB
// hfin : f32  [2][64][512] (plain)                                256 KiB
static const size_t WS_XS = 0;
static const size_t WS_W2 = (size_t)16 << 20;
static const size_t WS_HP = WS_W2 + 6291456;
static const size_t WS_HF = WS_HP + 524288;

__device__ __forceinline__ float fsigm(float x) { return 1.f / (1.f + __expf(-x)); }
__device__ __forceinline__ float ftanh(float x) {
  float e = __expf(2.f * fabsf(x));
  float r = 1.f - 2.f / (e + 1.f);
  return copysignf(r, x);
}

// Embedding gather + bf16 convert + granule swizzle.
__global__ void embed_swz_kernel(const int* __restrict__ sent,
                                 const float* __restrict__ emb,
                                 __bf16* __restrict__ xs_g) {
  int id = blockIdx.x * 256 + threadIdx.x;
  int gx = id & 31;          // granule within row (32 x 8 bf16 = 256)
  int b  = (id >> 5) & 63;
  int t  = id >> 11;
  int idx = sent[b * T_ + t];            // sentence is [B][T]
  const float* src = emb + (size_t)idx * E_ + gx * 8;
  bf16x8 v;
#pragma unroll
  for (int j = 0; j < 8; ++j) v[j] = (__bf16)src[j];
  int gs = gx ^ (b & 7);                 // XOR swizzle keyed by batch row
  *(bf16x8*)(xs_g + (size_t)(t * 64 + b) * E_ + gs * 8) = v;
}

// Weight prep (fragment-ordered for direct coalesced global->reg in lstm_main)
// + zero-init of the self-validating h publication buffer (epochs cleared —
// required every call so stale epochs from a previous replay can never match).
__global__ void __launch_bounds__(256)
wprep_kernel(const float* __restrict__ Wx_f, const float* __restrict__ Wh_f,
             const float* __restrict__ Wx_b, const float* __restrict__ Wh_b,
             __bf16* __restrict__ w2, u32* __restrict__ hpub) {
  int bid = blockIdx.x;              // ((d*16+us)*8+wv)*6 + jg
  int tid = threadIdx.x;
  {
    int zid = bid * 256 + tid;
    if (zid < 131072) hpub[zid] = 0u;
  }
  int jg = bid % 6;
  int wv = (bid / 6) & 7;
  int us = (bid / 48) & 15;
  int d  = bid / 768;
  int j    = jg * 4 + (tid >> 6);
  int lane = tid & 63;
  int c    = wv * 16 + (lane & 15);   // slice row 0..127
  int ul   = c >> 2, gate = c & 3;
  int n    = gate * 512 + us * 32 + ul;
  int k0   = j * 32 + (lane >> 4) * 8;
  const float* Wx = d ? Wx_b : Wx_f;
  const float* Wh = d ? Wh_b : Wh_f;
  bf16x8 v;
#pragma unroll
  for (int e = 0; e < 8; ++e) {
    int k = k0 + e;
    float f = (k < 256) ? Wx[(size_t)k * 2048 + n] : Wh[(size_t)(k - 256) * 2048 + n];
    v[e] = (__bf16)f;
  }
  size_t og = ((size_t)((d * 16 + us) * 8 + wv) * 24 + j) * 64 + lane;
  *(bf16x8*)(w2 + og * 8) = v;
}

// Persistent bidirectional LSTM. 128 WGs x 512 thr.
// WG = (dir, us 0..15, q 0..3): units 32us..+31, batches 16q..+15.
// hpub slice ([32 u][16 b] u32 words, (bf16 h)<<16 | epoch16): thread
// (wv,lane) owns word wv*64+lane -> each thread publishes its own word with
// one coalesced relaxed agent atomic right after gates (no staging, no flag).
// Consumers speculatively load 8 coalesced u64/thread, validate embedded
// epochs, retry on miss; pack hi16s into swizzled LDS [b][u] tile.
__global__ void __launch_bounds__(512)
lstm_main(const __bf16* __restrict__ xs_g, const __bf16* __restrict__ w2,
          u32* __restrict__ hpub, float* __restrict__ hfin,
          const float* __restrict__ b_f, const float* __restrict__ b_b) {
  __shared__ __align__(16) __bf16 xbuf[2][16 * 256];   // 2 x 8 KiB
  __shared__ __align__(16) __bf16 hbuf[16 * 512];      // 16 KiB

  const int wg   = blockIdx.x;
  const int dir  = wg >> 6;
  const int sl   = wg & 63;
  const int us   = sl >> 2;
  const int q    = sl & 3;
  const int tid  = threadIdx.x;
  const int wv   = tid >> 6;
  const int lane = tid & 63;
  const int bq_l = lane & 15;          // local batch / D col
  const int kq   = lane >> 4;          // k-quarter
  const int bsw  = bq_l & 7;           // swizzle key
  const int ul_own = wv * 4 + kq;      // owned local unit (0..31)
  const int u_own  = us * 32 + ul_own;
  const int b_own  = q * 16 + bq_l;

  // ---- weight fragments: direct coalesced global->reg ----
  bf16x8 wfrag[24];
  {
    const bf16x8* wp = (const bf16x8*)w2 +
                       ((size_t)((dir * 16 + us) * 8 + wv) * 24) * 64 + lane;
#pragma unroll
    for (int j = 0; j < 24; ++j) wfrag[j] = wp[j * 64];
  }

  const float* bias = dir ? b_b : b_f;
  const float bi  = bias[u_own];
  const float bff = bias[512 + u_own];
  const float bg  = bias[1024 + u_own];
  const float bo  = bias[1536 + u_own];
  float c_st = 0.f;

  // ---- producer word ptrs ([u][b]: word = ul_own*16 + bq_l = wv*64+lane) ----
  u32* const pw0 = hpub + ((size_t)(dir * 2 + 0) * 64 + q * 16 + us) * 512 + wv * 64 + lane;
  u32* const pw1 = pw0 + 32768;

  // ---- consumer: half-wave covers producer us_p's 2KB slice ----
  const int us_p  = 2 * wv + (lane >> 5);
  const int lane5 = lane & 31;
  const u64* const cs0 = (const u64*)(hpub + ((size_t)(dir * 2 + 0) * 64 + q * 16 + us_p) * 512) + lane5;
  const u64* const cs1 = cs0 + 16384;
  // u64 j covers words (u = us_p*32-local j*4 + lane5>>3, b = 2*(lane5&7), b+1)
  const int cc = lane5 >> 3;           // u sub-offset
  const int cb0 = 2 * (lane5 & 7);
  const int cb1 = cb0 + 1;
  int cd0[8], cd1[8];
#pragma unroll
  for (int j = 0; j < 8; ++j) {
    int u = us_p * 32 + j * 4 + cc;    // global unit within quarter's 512
    int g = u >> 3;
    cd0[j] = cb0 * 1024 + ((g ^ (cb0 & 7)) << 4) + ((u & 7) << 1);
    cd1[j] = cb1 * 1024 + ((g ^ (cb1 & 7)) << 4) + ((u & 7) << 1);
  }

  // ---- stage x_0 (8 KiB: 512 granules, 1 per thread) ----
  {
    int t0 = dir ? (T_ - 1) : 0;
    const uint4* xsrc = (const uint4*)(xs_g + ((size_t)t0 * 64 + q * 16) * 256);
    ((uint4*)xbuf[0])[tid] = xsrc[tid];
  }
  __syncthreads();

  for (int t = 0;; ++t) {
    const bool lastt = (t == T_ - 1);
    // ---- [P] speculative coalesced h loads (fly under x-MFMAs/validate) ----
    u64 v[8];
    const u64* csrc = (t & 1) ? cs1 : cs0;
    if (t > 0) {
#pragma unroll
      for (int j = 0; j < 8; ++j)
        v[j] = __hip_atomic_load(csrc + j * 32, __ATOMIC_RELAXED, __HIP_MEMORY_SCOPE_AGENT);
    }
    // ---- issue x_{t+1} global load early (consumed after publish) ----
    uint4 xg;
    if (!lastt) {
      const int teff = dir ? (T_ - 2 - t) : (t + 1);
      xg = ((const uint4*)(xs_g + ((size_t)teff * 64 + q * 16) * 256))[tid];
    }

    // ---- [A] x-part MFMAs ----
    f32x4 acc0 = {0.f, 0.f, 0.f, 0.f};
    f32x4 acc1 = {0.f, 0.f, 0.f, 0.f};
    const __bf16* xb = xbuf[t & 1];
#pragma unroll
    for (int j = 0; j < 8; ++j) {
      int g = j * 4 + kq;
      bf16x8 a = *(const bf16x8*)(xb + bq_l * 256 + ((g ^ bsw) << 3));
      if (j & 1) acc1 = __builtin_amdgcn_mfma_f32_16x16x32_bf16(wfrag[j], a, acc1, 0, 0, 0);
      else       acc0 = __builtin_amdgcn_mfma_f32_16x16x32_bf16(wfrag[j], a, acc0, 0, 0, 0);
    }

    if (t > 0) {
      // ---- [B] validate embedded epochs; retry until fresh ----
      const u32 ep = (u32)t;
      for (;;) {
        u32 bad = 0;
#pragma unroll
        for (int j = 0; j < 8; ++j)
          bad |= ((u32)v[j] ^ ep) | ((u32)(v[j] >> 32) ^ ep);
        bad &= 0xFFFFu;
        if (!__any((int)bad)) break;
        __builtin_amdgcn_s_sleep(1);
#pragma unroll
        for (int j = 0; j < 8; ++j)
          v[j] = __hip_atomic_load(csrc + j * 32, __ATOMIC_RELAXED, __HIP_MEMORY_SCOPE_AGENT);
      }
      // ---- [C] pack hi16s -> swizzled LDS [b][u] tile (16 x ds_write_b16) ----
#pragma unroll
      for (int j = 0; j < 8; ++j) {
        *(u16*)((char*)hbuf + cd0[j]) = (u16)(v[j] >> 16);
        *(u16*)((char*)hbuf + cd1[j]) = (u16)(v[j] >> 48);
      }
      __syncthreads();   // S1: hbuf complete
      // ---- [D] h-part MFMAs ----
#pragma unroll
      for (int j = 0; j < 16; ++j) {
        int g = j * 4 + kq;
        bf16x8 a = *(const bf16x8*)(hbuf + bq_l * 512 + ((g ^ bsw) << 3));
        if (j & 1) acc1 = __builtin_amdgcn_mfma_f32_16x16x32_bf16(wfrag[8 + j], a, acc1, 0, 0, 0);
        else       acc0 = __builtin_amdgcn_mfma_f32_16x16x32_bf16(wfrag[8 + j], a, acc0, 0, 0, 0);
      }
    }

    // ---- gates in registers ----
    const float zi = acc0[0] + acc1[0] + bi;
    const float zf = acc0[1] + acc1[1] + bff;
    const float zg = acc0[2] + acc1[2] + bg;
    const float zo = acc0[3] + acc1[3] + bo;
    c_st = fsigm(zf) * c_st + fsigm(zi) * ftanh(zg);
    const float hv = fsigm(zo) * ftanh(c_st);

    if (lastt) {
      hfin[(size_t)dir * 32768 + b_own * 512 + u_own] = hv;
      break;
    }

    // ---- [E] publish own word immediately (coalesced, fire-and-forget) ----
    {
      union { __bf16 h; u16 s; } cv;
      cv.h = (__bf16)hv;
      u32 word = ((u32)cv.s << 16) | (u32)(t + 1);
      __hip_atomic_store(((t + 1) & 1) ? pw1 : pw0, word, __ATOMIC_RELAXED,
                         __HIP_MEMORY_SCOPE_AGENT);
    }
    // ---- complete x_{t+1} staging (load already in flight) ----
    ((uint4*)xbuf[(t + 1) & 1])[tid] = xg;
    __syncthreads();   // S2: xbuf ready; hbuf/xbuf reads done before next step
  }
}

// Final head: out = sigmoid((hcat @ W1 + b1) @ W2 + b2), all f32. One block.
__global__ void __launch_bounds__(1024)
dense_kernel(const float* __restrict__ hfin, const float* __restrict__ W1,
             const float* __restrict__ b1, const float* __restrict__ W2,
             const float* __restrict__ b2, float* __restrict__ out) {
  __shared__ float hid[64][64];
  const int t = threadIdx.x;
  const int b = t >> 4;
  const int jg = t & 15;           // 4 output cols each
  float a0 = b1[jg * 4 + 0], a1 = b1[jg * 4 + 1], a2 = b1[jg * 4 + 2], a3 = b1[jg * 4 + 3];
#pragma unroll 8
  for (int k = 0; k < 1024; ++k) {
    const float hv = hfin[(size_t)(k >> 9) * 32768 + b * 512 + (k & 511)];
    const float4 w = *(const float4*)(W1 + (size_t)k * 64 + jg * 4);
    a0 += hv * w.x; a1 += hv * w.y; a2 += hv * w.z; a3 += hv * w.w;
  }
  hid[b][jg * 4 + 0] = a0; hid[b][jg * 4 + 1] = a1;
  hid[b][jg * 4 + 2] = a2; hid[b][jg * 4 + 3] = a3;
  __syncthreads();
  if (t < 64) {
    float l = b2[0];
#pragma unroll 8
    for (int j = 0; j < 64; ++j) l += hid[t][j] * W2[j];
    out[t] = 1.f / (1.f + __expf(-l));
  }
}

extern "C" void kernel_launch(void* const* d_in, const int* in_sizes, int n_in,
                              void* d_out, int out_size, void* d_ws, size_t ws_size,
                              hipStream_t stream) {
  const int*   sent = (const int*)d_in[0];
  const float* emb  = (const float*)d_in[1];
  const float* Wx_f = (const float*)d_in[2];
  const float* Wh_f = (const float*)d_in[3];
  const float* b_f  = (const float*)d_in[4];
  const float* Wx_b = (const float*)d_in[5];
  const float* Wh_b = (const float*)d_in[6];
  const float* b_b  = (const float*)d_in[7];
  const float* W1   = (const float*)d_in[8];
  const float* b1   = (const float*)d_in[9];
  const float* W2   = (const float*)d_in[10];
  const float* b2   = (const float*)d_in[11];
  float* out = (float*)d_out;

  char* ws = (char*)d_ws;
  __bf16* xs_g = (__bf16*)(ws + WS_XS);
  __bf16* w2   = (__bf16*)(ws + WS_W2);
  u32*    hpub = (u32*)(ws + WS_HP);
  float*  hfin = (float*)(ws + WS_HF);

  hipLaunchKernelGGL(embed_swz_kernel, dim3(4096), dim3(256), 0, stream, sent, emb, xs_g);
  hipLaunchKernelGGL(wprep_kernel, dim3(1536), dim3(256), 0, stream,
                     Wx_f, Wh_f, Wx_b, Wh_b, w2, hpub);

  void* args[] = {(void*)&xs_g, (void*)&w2, (void*)&hpub, (void*)&hfin,
                  (void*)&b_f, (void*)&b_b};
  hipLaunchCooperativeKernel((void*)lstm_main, dim3(128), dim3(512), args, 0, stream);

  hipLaunchKernelGGL(dense_kernel, dim3(1), dim3(1024), 0, stream,
                     hfin, W1, b1, W2, b2, out);
}